// Round 1
// baseline (34931.641 us; speedup 1.0000x reference)
//
#include <hip/hip_runtime.h>
#include <hip/hip_bf16.h>

#define T_STEPS 2048
#define BATCH 32
#define DIN 512
#define HID 512
#define G4H 2048
#define NWG 64
#define SLICE 8     // HID / NWG hidden indices per WG
#define THREADS 256

typedef __attribute__((ext_vector_type(8))) short short8;
typedef __attribute__((ext_vector_type(4))) float floatx4;

__device__ __forceinline__ ushort f2bf(float f) {
  return __builtin_bit_cast(ushort, __float2bfloat16(f));
}

// One-shot prep: bf16 weights, combined bias, bf16 h0, zero barrier.
__global__ void prep_kernel(const float* __restrict__ wih, const float* __restrict__ whh,
                            const float* __restrict__ bih, const float* __restrict__ bhh,
                            const float* __restrict__ h0,
                            ushort* __restrict__ wihb, ushort* __restrict__ whhb,
                            float* __restrict__ bias, ushort* __restrict__ hbuf,
                            unsigned* __restrict__ bar) {
  int i = blockIdx.x * blockDim.x + threadIdx.x;
  const int NW = G4H * DIN;
  if (i < NW) { wihb[i] = f2bf(wih[i]); whhb[i] = f2bf(whh[i]); }
  if (i < G4H) bias[i] = bih[i] + bhh[i];
  if (i < BATCH * HID) hbuf[i] = f2bf(h0[i]);
  if (i == 0) *bar = 0u;
}

__global__ void cvtx_kernel(const float* __restrict__ x, ushort* __restrict__ xb) {
  const size_t N = (size_t)T_STEPS * BATCH * DIN;
  size_t stride = (size_t)gridDim.x * blockDim.x * 4;
  for (size_t idx = ((size_t)blockIdx.x * blockDim.x + threadIdx.x) * 4; idx < N; idx += stride) {
    float4 f = *reinterpret_cast<const float4*>(x + idx);
    ushort4 u;
    u.x = f2bf(f.x); u.y = f2bf(f.y); u.z = f2bf(f.z); u.w = f2bf(f.w);
    *reinterpret_cast<ushort4*>(xb + idx) = u;
  }
}

// Persistent cooperative LSTM kernel.
// WG g owns hidden slice [g*8, g*8+8) -> 32 gate columns (j = kk*4 + q,
// global gate row = q*512 + g*8 + kk). Wave (r,cc): 16x16 tile, rows r*16..,
// cols cc*16... A-frag: A[m=lane&15][k=quad*8+j]; B-frag mirrors with
// n=lane&15. C/D: col=lane&15, row=quad*4+reg.
template <bool XB>
__global__ __launch_bounds__(THREADS, 1) void lstm_kernel(
    const float* __restrict__ x, const ushort* __restrict__ xb,
    const float* __restrict__ c0,
    const ushort* __restrict__ wihb, const ushort* __restrict__ whhb,
    const float* __restrict__ bias, ushort* __restrict__ hbuf,
    float* __restrict__ out, unsigned* __restrict__ bar) {
  const int g = blockIdx.x;
  const int tid = threadIdx.x;
  const int lane = tid & 63;
  const int wave = tid >> 6;
  const int r = wave & 1;        // batch row tile
  const int cc = wave >> 1;      // column tile
  const int n16 = lane & 15;
  const int quad = lane >> 4;
  const int brow = r * 16 + n16; // batch row for A-frag loads

  const int j = cc * 16 + n16;                           // WG-local gate col 0..31
  const int wrow = (j & 3) * HID + g * SLICE + (j >> 2); // global gate row 0..2047

  // elementwise ownership: one (b, k) per thread
  const int eb = tid >> 3;
  const int ekk = tid & 7;
  const int ecol = g * SLICE + ekk;
  float c_val = c0[eb * HID + ecol];
  const float bi = bias[ecol];
  const float bf_ = bias[HID + ecol];
  const float bg = bias[2 * HID + ecol];
  const float bo = bias[3 * HID + ecol];

  // Weights resident in registers for the whole run (2x64 VGPRs).
  short8 wih_r[16], whh_r[16];
  {
    const ushort* wr = wihb + (size_t)wrow * DIN + quad * 8;
    const ushort* hr = whhb + (size_t)wrow * HID + quad * 8;
#pragma unroll
    for (int kb = 0; kb < 16; ++kb) {
      wih_r[kb] = *reinterpret_cast<const short8*>(wr + kb * 32);
      whh_r[kb] = *reinterpret_cast<const short8*>(hr + kb * 32);
    }
  }

  __shared__ float gsm[32][33];

  float hlast = 0.f;
  for (int t = 0; t < T_STEPS; ++t) {
    const int par = t & 1;
    const ushort* hp = hbuf + par * (BATCH * HID) + brow * HID + quad * 8;
    floatx4 acc0 = {0.f, 0.f, 0.f, 0.f};
    floatx4 acc1 = {0.f, 0.f, 0.f, 0.f};
    if (XB) {
      const ushort* xt = xb + ((size_t)t * BATCH + brow) * DIN + quad * 8;
#pragma unroll
      for (int kb = 0; kb < 16; ++kb) {
        short8 a0 = *reinterpret_cast<const short8*>(xt + kb * 32);
        short8 a1 = *reinterpret_cast<const short8*>(hp + kb * 32);
        acc0 = __builtin_amdgcn_mfma_f32_16x16x32_bf16(a0, wih_r[kb], acc0, 0, 0, 0);
        acc1 = __builtin_amdgcn_mfma_f32_16x16x32_bf16(a1, whh_r[kb], acc1, 0, 0, 0);
      }
    } else {
      const float* xt = x + ((size_t)t * BATCH + brow) * DIN + quad * 8;
#pragma unroll
      for (int kb = 0; kb < 16; ++kb) {
        const float4* xp = reinterpret_cast<const float4*>(xt + kb * 32);
        float4 f0 = xp[0], f1 = xp[1];
        short8 a0;
        a0[0] = (short)f2bf(f0.x); a0[1] = (short)f2bf(f0.y);
        a0[2] = (short)f2bf(f0.z); a0[3] = (short)f2bf(f0.w);
        a0[4] = (short)f2bf(f1.x); a0[5] = (short)f2bf(f1.y);
        a0[6] = (short)f2bf(f1.z); a0[7] = (short)f2bf(f1.w);
        short8 a1 = *reinterpret_cast<const short8*>(hp + kb * 32);
        acc0 = __builtin_amdgcn_mfma_f32_16x16x32_bf16(a0, wih_r[kb], acc0, 0, 0, 0);
        acc1 = __builtin_amdgcn_mfma_f32_16x16x32_bf16(a1, whh_r[kb], acc1, 0, 0, 0);
      }
    }
    // scatter gate pre-activations to LDS (C-layout -> [b][j])
#pragma unroll
    for (int rg = 0; rg < 4; ++rg) {
      gsm[r * 16 + quad * 4 + rg][cc * 16 + n16] = acc0[rg] + acc1[rg];
    }
    __syncthreads();
    float pi = gsm[eb][ekk * 4 + 0] + bi;
    float pf = gsm[eb][ekk * 4 + 1] + bf_;
    float pg = gsm[eb][ekk * 4 + 2] + bg;
    float po = gsm[eb][ekk * 4 + 3] + bo;
    float ig = 1.f / (1.f + __expf(-pi));
    float fg = 1.f / (1.f + __expf(-pf));
    float eg = __expf(2.f * pg);
    float gg = 1.f - 2.f / (eg + 1.f);      // tanh
    float og = 1.f / (1.f + __expf(-po));
    c_val = fg * c_val + ig * gg;
    float ec = __expf(2.f * c_val);
    float tc = 1.f - 2.f / (ec + 1.f);      // tanh(c)
    float h = og * tc;
    hlast = h;
    out[(size_t)t * (BATCH * HID) + eb * HID + ecol] = h;
    hbuf[(par ^ 1) * (BATCH * HID) + eb * HID + ecol] = f2bf(h);

    // device-wide barrier: release h_t, arrive, spin, acquire
    __threadfence();
    __syncthreads();
    if (tid == 0) {
      __hip_atomic_fetch_add(bar, 1u, __ATOMIC_RELEASE, __HIP_MEMORY_SCOPE_AGENT);
      const unsigned target = (unsigned)(NWG * (t + 1));
      while (__hip_atomic_load(bar, __ATOMIC_ACQUIRE, __HIP_MEMORY_SCOPE_AGENT) < target) {
        __builtin_amdgcn_s_sleep(1);
      }
    }
    __syncthreads();
    __threadfence();
  }
  // tail outputs: h_n, c_n
  out[(size_t)T_STEPS * BATCH * HID + eb * HID + ecol] = hlast;
  out[(size_t)T_STEPS * BATCH * HID + BATCH * HID + eb * HID + ecol] = c_val;
}

extern "C" void kernel_launch(void* const* d_in, const int* in_sizes, int n_in,
                              void* d_out, int out_size, void* d_ws, size_t ws_size,
                              hipStream_t stream) {
  const float* x = (const float*)d_in[0];
  const float* h0 = (const float*)d_in[1];
  const float* c0 = (const float*)d_in[2];
  const float* w_ih = (const float*)d_in[3];
  const float* b_ih = (const float*)d_in[4];
  const float* w_hh = (const float*)d_in[5];
  const float* b_hh = (const float*)d_in[6];
  float* out = (float*)d_out;
  char* ws = (char*)d_ws;

  // workspace layout
  unsigned* bar = (unsigned*)ws;                              // 256 B
  float* bias = (float*)(ws + 1024);                          // 8 KB
  ushort* wihb = (ushort*)(ws + (16 << 10));                  // 2 MB
  ushort* whhb = (ushort*)(ws + (16 << 10) + (2 << 20));      // 2 MB
  ushort* hbuf = (ushort*)(ws + (16 << 10) + (4 << 20));      // 64 KB (double buffer)
  ushort* xb = (ushort*)(ws + (8 << 20));                     // 64 MB (optional)
  const size_t xb_bytes = (size_t)T_STEPS * BATCH * DIN * sizeof(ushort);
  const bool use_xb = ws_size >= ((size_t)(8 << 20) + xb_bytes);

  hipLaunchKernelGGL(prep_kernel, dim3(4096), dim3(256), 0, stream,
                     w_ih, w_hh, b_ih, b_hh, h0, wihb, whhb, bias, hbuf, bar);

  if (use_xb) {
    hipLaunchKernelGGL(cvtx_kernel, dim3(8192), dim3(256), 0, stream, x, xb);
    void* args[] = {(void*)&x, (void*)&xb, (void*)&c0, (void*)&wihb, (void*)&whhb,
                    (void*)&bias, (void*)&hbuf, (void*)&out, (void*)&bar};
    hipLaunchCooperativeKernel(reinterpret_cast<void*>(&lstm_kernel<true>),
                               dim3(NWG), dim3(THREADS), args, 0, stream);
  } else {
    void* args[] = {(void*)&x, (void*)&xb, (void*)&c0, (void*)&wihb, (void*)&whhb,
                    (void*)&bias, (void*)&hbuf, (void*)&out, (void*)&bar};
    hipLaunchCooperativeKernel(reinterpret_cast<void*>(&lstm_kernel<false>),
                               dim3(NWG), dim3(THREADS), args, 0, stream);
  }
}

// Round 2
// 21342.673 us; speedup vs baseline: 1.6367x; 1.6367x over previous
//
#include <hip/hip_runtime.h>
#include <hip/hip_bf16.h>

#define T_STEPS 2048
#define BATCH 32
#define DIN 512
#define HID 512
#define G4H 2048
#define NWG 64
#define SLICE 8     // HID / NWG hidden indices per WG
#define THREADS 256

typedef __attribute__((ext_vector_type(8))) short short8;
typedef __attribute__((ext_vector_type(4))) float floatx4;
typedef unsigned long long ull;

__device__ __forceinline__ ushort f2bf(float f) {
  return __builtin_bit_cast(ushort, __float2bfloat16(f));
}

// One-shot prep: bf16 weights, combined bias, bf16 h0, zero flags.
__global__ void prep_kernel(const float* __restrict__ wih, const float* __restrict__ whh,
                            const float* __restrict__ bih, const float* __restrict__ bhh,
                            const float* __restrict__ h0,
                            ushort* __restrict__ wihb, ushort* __restrict__ whhb,
                            float* __restrict__ bias, ushort* __restrict__ hbuf,
                            unsigned* __restrict__ flags) {
  int i = blockIdx.x * blockDim.x + threadIdx.x;
  const int NW = G4H * DIN;
  if (i < NW) { wihb[i] = f2bf(wih[i]); whhb[i] = f2bf(whh[i]); }
  if (i < G4H) bias[i] = bih[i] + bhh[i];
  if (i < BATCH * HID) hbuf[i] = f2bf(h0[i]);
  if (i < 4 * NWG) flags[i] = 0u;
}

__global__ void cvtx_kernel(const float* __restrict__ x, ushort* __restrict__ xb) {
  const size_t N = (size_t)T_STEPS * BATCH * DIN;
  size_t stride = (size_t)gridDim.x * blockDim.x * 4;
  for (size_t idx = ((size_t)blockIdx.x * blockDim.x + threadIdx.x) * 4; idx < N; idx += stride) {
    float4 f = *reinterpret_cast<const float4*>(x + idx);
    ushort4 u;
    u.x = f2bf(f.x); u.y = f2bf(f.y); u.z = f2bf(f.z); u.w = f2bf(f.w);
    *reinterpret_cast<ushort4*>(xb + idx) = u;
  }
}

// x-part MFMA for timestep t (h-independent).
template <bool XB>
__device__ __forceinline__ floatx4 xpart(const float* __restrict__ x,
                                         const ushort* __restrict__ xb,
                                         int t, int brow, int quad,
                                         const short8* wih_r) {
  floatx4 acc = {0.f, 0.f, 0.f, 0.f};
  if (XB) {
    const ushort* xt = xb + ((size_t)t * BATCH + brow) * DIN + quad * 8;
#pragma unroll
    for (int kb = 0; kb < 16; ++kb) {
      short8 a0 = *reinterpret_cast<const short8*>(xt + kb * 32);
      acc = __builtin_amdgcn_mfma_f32_16x16x32_bf16(a0, wih_r[kb], acc, 0, 0, 0);
    }
  } else {
    const float* xt = x + ((size_t)t * BATCH + brow) * DIN + quad * 8;
#pragma unroll
    for (int kb = 0; kb < 16; ++kb) {
      const float4* xp = reinterpret_cast<const float4*>(xt + kb * 32);
      float4 f0 = xp[0], f1 = xp[1];
      short8 a0;
      a0[0] = (short)f2bf(f0.x); a0[1] = (short)f2bf(f0.y);
      a0[2] = (short)f2bf(f0.z); a0[3] = (short)f2bf(f0.w);
      a0[4] = (short)f2bf(f1.x); a0[5] = (short)f2bf(f1.y);
      a0[6] = (short)f2bf(f1.z); a0[7] = (short)f2bf(f1.w);
      acc = __builtin_amdgcn_mfma_f32_16x16x32_bf16(a0, wih_r[kb], acc, 0, 0, 0);
    }
  }
  return acc;
}

// Persistent cooperative LSTM kernel. Cross-WG h-state exchange via relaxed
// agent-scope atomics only (per-access sc bits -> coherence point; NO
// buffer_wbl2 / buffer_inv cache maintenance, which dominated round-1 at
// ~15.6us/step). Per-wave flags (4 per WG) so each wave publishes and polls
// independently; one __syncthreads per step (gsm double-buffered).
template <bool XB>
__global__ __launch_bounds__(THREADS, 1) void lstm_kernel(
    const float* __restrict__ x, const ushort* __restrict__ xb,
    const float* __restrict__ c0,
    const ushort* __restrict__ wihb, const ushort* __restrict__ whhb,
    const float* __restrict__ bias, ushort* __restrict__ hbuf,
    float* __restrict__ out, unsigned* __restrict__ flags) {
  const int g = blockIdx.x;
  const int tid = threadIdx.x;
  const int lane = tid & 63;
  const int wave = tid >> 6;
  const int r = wave & 1;        // batch row tile
  const int cc = wave >> 1;      // column tile
  const int n16 = lane & 15;
  const int quad = lane >> 4;
  const int brow = r * 16 + n16; // batch row for A-frag loads

  const int j = cc * 16 + n16;                           // WG-local gate col 0..31
  const int wrow = (j & 3) * HID + g * SLICE + (j >> 2); // global gate row 0..2047

  // elementwise ownership: one (b, k) per thread
  const int eb = tid >> 3;
  const int ekk = tid & 7;
  const int ecol = g * SLICE + ekk;
  float c_val = c0[eb * HID + ecol];
  const float bi = bias[ecol];
  const float bf_ = bias[HID + ecol];
  const float bg = bias[2 * HID + ecol];
  const float bo = bias[3 * HID + ecol];

  // Weights resident in registers for the whole run.
  short8 wih_r[16], whh_r[16];
  {
    const ushort* wr = wihb + (size_t)wrow * DIN + quad * 8;
    const ushort* hr = whhb + (size_t)wrow * HID + quad * 8;
#pragma unroll
    for (int kb = 0; kb < 16; ++kb) {
      wih_r[kb] = *reinterpret_cast<const short8*>(wr + kb * 32);
      whh_r[kb] = *reinterpret_cast<const short8*>(hr + kb * 32);
    }
  }

  __shared__ float gsm[2][32][33];

  // prologue: x-part for t=0
  floatx4 acc0_cur = xpart<XB>(x, xb, 0, brow, quad, wih_r);

  float hlast = 0.f;
  for (int t = 0; t < T_STEPS; ++t) {
    const int par = t & 1;
    // ---- per-wave poll: wait until all 4*NWG wave-flags >= t ----
    if (t) {
      const ull* fp = reinterpret_cast<const ull*>(flags) + 2 * lane;
      const unsigned tgt = (unsigned)t;
      for (;;) {
        ull a = __hip_atomic_load(fp, __ATOMIC_RELAXED, __HIP_MEMORY_SCOPE_AGENT);
        ull b = __hip_atomic_load(fp + 1, __ATOMIC_RELAXED, __HIP_MEMORY_SCOPE_AGENT);
        unsigned t0 = (unsigned)a, t1 = (unsigned)(a >> 32);
        unsigned t2 = (unsigned)b, t3 = (unsigned)(b >> 32);
        unsigned mn = t0 < t1 ? t0 : t1;
        unsigned mn2 = t2 < t3 ? t2 : t3;
        if (mn2 < mn) mn = mn2;
        if (__all(mn >= tgt)) break;
        __builtin_amdgcn_s_sleep(1);
      }
    }
    __atomic_signal_fence(__ATOMIC_SEQ_CST);

    // ---- issue h_t A-frag loads (coherence-point reads) ----
    const ull* hp = reinterpret_cast<const ull*>(
        hbuf + (size_t)par * (BATCH * HID) + brow * HID + quad * 8);
    ull hl[32];
#pragma unroll
    for (int kb = 0; kb < 16; ++kb) {
      hl[2 * kb]     = __hip_atomic_load(hp + kb * 8,     __ATOMIC_RELAXED, __HIP_MEMORY_SCOPE_AGENT);
      hl[2 * kb + 1] = __hip_atomic_load(hp + kb * 8 + 1, __ATOMIC_RELAXED, __HIP_MEMORY_SCOPE_AGENT);
    }

    // ---- x-part for t+1 while h loads are in flight ----
    const int tt = (t + 1 < T_STEPS) ? t + 1 : t;
    floatx4 acc0_next = xpart<XB>(x, xb, tt, brow, quad, wih_r);

    // ---- h-part MFMAs ----
    floatx4 acc1 = {0.f, 0.f, 0.f, 0.f};
#pragma unroll
    for (int kb = 0; kb < 16; ++kb) {
      union { ull u[2]; short8 s; } cv;
      cv.u[0] = hl[2 * kb];
      cv.u[1] = hl[2 * kb + 1];
      acc1 = __builtin_amdgcn_mfma_f32_16x16x32_bf16(cv.s, whh_r[kb], acc1, 0, 0, 0);
    }

    // ---- scatter gates to LDS (C-layout -> [b][j]) ----
#pragma unroll
    for (int rg = 0; rg < 4; ++rg) {
      gsm[par][r * 16 + quad * 4 + rg][cc * 16 + n16] = acc0_cur[rg] + acc1[rg];
    }
    __syncthreads();

    // ---- elementwise ----
    float pi = gsm[par][eb][ekk * 4 + 0] + bi;
    float pf = gsm[par][eb][ekk * 4 + 1] + bf_;
    float pg = gsm[par][eb][ekk * 4 + 2] + bg;
    float po = gsm[par][eb][ekk * 4 + 3] + bo;
    float ig = 1.f / (1.f + __expf(-pi));
    float fg = 1.f / (1.f + __expf(-pf));
    float eg = __expf(2.f * pg);
    float gg = 1.f - 2.f / (eg + 1.f);      // tanh
    float og = 1.f / (1.f + __expf(-po));
    c_val = fg * c_val + ig * gg;
    float ec = __expf(2.f * c_val);
    float tc = 1.f - 2.f / (ec + 1.f);      // tanh(c)
    float h = og * tc;
    hlast = h;
    out[(size_t)t * (BATCH * HID) + eb * HID + ecol] = h;

    // ---- pack h to bf16 via in-wave shuffles; 8B atomic store ----
    int m = (int)f2bf(h) & 0xffff;
    int p0 = __shfl(m, lane & ~1);
    int p1 = __shfl(m, (lane & ~1) | 1);
    int u32v = p0 | (p1 << 16);
    int q0 = __shfl(u32v, lane & ~3);
    int q2 = __shfl(u32v, (lane & ~3) | 2);
    ull v64 = ((ull)(unsigned)q0) | (((ull)(unsigned)q2) << 32);
    if ((lane & 3) == 0) {
      int p = lane >> 2;
      int idx = (wave * 8 + (p >> 1)) * HID + g * SLICE + (p & 1) * 4;  // ushort index
      ull* dst = reinterpret_cast<ull*>(hbuf + (size_t)(par ^ 1) * (BATCH * HID) + idx);
      __hip_atomic_store(dst, v64, __ATOMIC_RELAXED, __HIP_MEMORY_SCOPE_AGENT);
    }
    // order: h stores visible at coherence point before flag store
    __atomic_signal_fence(__ATOMIC_SEQ_CST);
    __builtin_amdgcn_s_waitcnt(0);
    __atomic_signal_fence(__ATOMIC_SEQ_CST);
    if (lane == 0) {
      __hip_atomic_store(&flags[g * 4 + wave], (unsigned)(t + 1),
                         __ATOMIC_RELAXED, __HIP_MEMORY_SCOPE_AGENT);
    }
    acc0_cur = acc0_next;
  }
  // tail outputs: h_n, c_n
  out[(size_t)T_STEPS * BATCH * HID + eb * HID + ecol] = hlast;
  out[(size_t)T_STEPS * BATCH * HID + BATCH * HID + eb * HID + ecol] = c_val;
}

extern "C" void kernel_launch(void* const* d_in, const int* in_sizes, int n_in,
                              void* d_out, int out_size, void* d_ws, size_t ws_size,
                              hipStream_t stream) {
  const float* x = (const float*)d_in[0];
  const float* h0 = (const float*)d_in[1];
  const float* c0 = (const float*)d_in[2];
  const float* w_ih = (const float*)d_in[3];
  const float* b_ih = (const float*)d_in[4];
  const float* w_hh = (const float*)d_in[5];
  const float* b_hh = (const float*)d_in[6];
  float* out = (float*)d_out;
  char* ws = (char*)d_ws;

  // workspace layout
  unsigned* flags = (unsigned*)ws;                            // 1 KB (256 wave-flags)
  float* bias = (float*)(ws + 1024);                          // 8 KB
  ushort* wihb = (ushort*)(ws + (16 << 10));                  // 2 MB
  ushort* whhb = (ushort*)(ws + (16 << 10) + (2 << 20));      // 2 MB
  ushort* hbuf = (ushort*)(ws + (16 << 10) + (4 << 20));      // 128 KB (double buffer)
  ushort* xb = (ushort*)(ws + (8 << 20));                     // 64 MB (optional)
  const size_t xb_bytes = (size_t)T_STEPS * BATCH * DIN * sizeof(ushort);
  const bool use_xb = ws_size >= ((size_t)(8 << 20) + xb_bytes);

  hipLaunchKernelGGL(prep_kernel, dim3(4096), dim3(256), 0, stream,
                     w_ih, w_hh, b_ih, b_hh, h0, wihb, whhb, bias, hbuf, flags);

  if (use_xb) {
    hipLaunchKernelGGL(cvtx_kernel, dim3(8192), dim3(256), 0, stream, x, xb);
    void* args[] = {(void*)&x, (void*)&xb, (void*)&c0, (void*)&wihb, (void*)&whhb,
                    (void*)&bias, (void*)&hbuf, (void*)&out, (void*)&flags};
    hipLaunchCooperativeKernel(reinterpret_cast<void*>(&lstm_kernel<true>),
                               dim3(NWG), dim3(THREADS), args, 0, stream);
  } else {
    void* args[] = {(void*)&x, (void*)&xb, (void*)&c0, (void*)&wihb, (void*)&whhb,
                    (void*)&bias, (void*)&hbuf, (void*)&out, (void*)&flags};
    hipLaunchCooperativeKernel(reinterpret_cast<void*>(&lstm_kernel<false>),
                               dim3(NWG), dim3(THREADS), args, 0, stream);
  }
}